// Round 2
// baseline (337.477 us; speedup 1.0000x reference)
//
#include <hip/hip_runtime.h>
#include <math.h>

namespace {
constexpr int kB = 8;
constexpr int kC = 256;
constexpr int kH = 128;
constexpr int kW = 128;
constexpr int kHW = kH * kW;     // 16384
constexpr int kTopK = 10;
constexpr float kThreshold = 0.5f;
constexpr float kMargin = 0.5f;
constexpr float kEps = 1e-8f;
constexpr int kMaps = 2 * kB;            // 8 loc maps then 8 det maps
constexpr int kGrpPlanes = 16;           // channel planes per group
constexpr int kGroups = kC / kGrpPlanes; // 16 groups per map
constexpr int kQuarter = kHW / 4;        // 4096 pixels per quarter
constexpr int kBands = 16;               // row bands per map (peak/topk)
constexpr int kBandRows = kH / kBands;   // 8 rows per band
}

// ---------------------------------------------------------------------------
// Kernel 1: partial[m][g][p] = sum_{c in group g} fmap[c][p]^2.
// INFLIGHT EXPERIMENT (round 2): round 1's __launch_bounds__(512,8) capped
// VGPR at 64 and the allocator serialized the 8-deep batch down to VGPR=24
// (~2 loads in flight) -> same ~64 KB/CU inflight as round 0 -> same 2.4 TB/s.
// This version: cap 128 VGPR (512,4) = 16 waves/CU, and a 16-deep load batch
// (8 planes x 2 float4 slots = 64 data VGPRs + 8 acc + addrs ~= 90, fits with
// headroom). Per-CU inflight = 16 waves * 16 KB = 256 KB, 4x rounds 0/1.
// Accumulation stays plane-ascending -> bitwise-identical partials.
// ---------------------------------------------------------------------------
__global__ __launch_bounds__(512, 4) void sumsq_kernel(
    const float* __restrict__ loc, const float* __restrict__ det,
    float* __restrict__ partial) {
  const int bid = blockIdx.x;   // 16 maps * 16 groups * 4 quarters = 1024
  const int m = bid >> 6;       // map 0..15
  const int g = (bid >> 2) & 15;
  const int q = bid & 3;
  const int t = threadIdx.x;    // 0..511
  const float* __restrict__ src = (m < kB) ? loc : det;
  const int b = m & (kB - 1);
  // thread t owns float4 slots {t, t+512} of the quarter's 1024 float4s
  const float* base = src + (size_t)b * kC * kHW +
                      (size_t)(g * kGrpPlanes) * kHW + q * kQuarter + t * 4;
  float4 a0 = {0.f, 0.f, 0.f, 0.f};
  float4 a1 = {0.f, 0.f, 0.f, 0.f};
  for (int j = 0; j < kGrpPlanes; j += 8) {  // 8-plane batches: 16 loads deep
    float4 v[16];
#pragma unroll
    for (int jj = 0; jj < 8; ++jj) {
      const float* pb = base + (size_t)(j + jj) * kHW;
      v[2 * jj] = *(const float4*)pb;
      v[2 * jj + 1] = *(const float4*)(pb + 2048);
    }
    __builtin_amdgcn_sched_barrier(0);  // all 16 loads issue before any use
#pragma unroll
    for (int jj = 0; jj < 8; ++jj) {
      const float4 u = v[2 * jj];
      const float4 x = v[2 * jj + 1];
      a0.x = fmaf(u.x, u.x, a0.x);
      a0.y = fmaf(u.y, u.y, a0.y);
      a0.z = fmaf(u.z, u.z, a0.z);
      a0.w = fmaf(u.w, u.w, a0.w);
      a1.x = fmaf(x.x, x.x, a1.x);
      a1.y = fmaf(x.y, x.y, a1.y);
      a1.z = fmaf(x.z, x.z, a1.z);
      a1.w = fmaf(x.w, x.w, a1.w);
    }
  }
  float* out = partial + ((size_t)m * kGroups + g) * kHW + q * kQuarter + t * 4;
  *(float4*)out = a0;
  *(float4*)(out + 2048) = a1;
}

// ---------------------------------------------------------------------------
// Kernel 2: fused combine + 3x3 peak mask + BLOCK-LOCAL top-10.
// One block per (map, 8-row band): 256 blocks. Recomputes a 2-row intensity
// halo from partial (group-sum order g=0..15 ascending -> bitwise-identical
// to a separate combine pass), sqrt into an LDS tile, evaluates the peak
// mask, then per-wave shfl-butterfly top-10 + wave-0 merge of the 4 wave
// lists -> 10 (val,idx) candidates per band.
// ---------------------------------------------------------------------------
__global__ __launch_bounds__(256) void peaktop_kernel(
    const float* __restrict__ partial, float* __restrict__ cvals,
    int* __restrict__ cidx) {
  const int m = blockIdx.x >> 4;
  const int band = blockIdx.x & 15;
  const int r0 = band * kBandRows;  // first output row
  const int t = threadIdx.x;        // 0..255
  const int w = t >> 6;
  const int lane = t & 63;
  __shared__ float ld[kBandRows + 2][kW + 4];  // 10 x 132 intensity tile
  __shared__ float swv[4][kTopK];
  __shared__ int swi[4][kTopK];

  // Intensity for rows [r0-1, r0+8]; OOB halo rows become -inf.
  const int prow0 = r0 - 1;  // tile row 0 <-> global row prow0
  float acc[5] = {0.f, 0.f, 0.f, 0.f, 0.f};
  const float* pbase = partial + (size_t)m * kGroups * kHW + prow0 * kW;
#pragma unroll 4
  for (int g = 0; g < kGroups; ++g) {
    const float* pg = pbase + (size_t)g * kHW;
#pragma unroll
    for (int i = 0; i < 5; ++i) {
      const int p = t + 256 * i;  // 0..1279 (10 rows x 128 cols)
      const int gr = prow0 + (p >> 7);
      if (gr >= 0 && gr < kH) acc[i] += pg[p];
    }
  }
#pragma unroll
  for (int i = 0; i < 5; ++i) {
    const int p = t + 256 * i;
    const int gr = prow0 + (p >> 7);
    ld[p >> 7][p & 127] = (gr >= 0 && gr < kH) ? sqrtf(acc[i]) : -INFINITY;
  }
  __syncthreads();

  // Peak candidates for the band's 1024 output pixels (4 per thread).
  float cv[4];
  int ci[4];
#pragma unroll
  for (int i = 0; i < 4; ++i) {
    const int op = t + 256 * i;        // 0..1023
    const int tr = (op >> 7) + 1;      // tile row 1..8
    const int col = op & 127;
    const float c0 = ld[tr][col];
    float nmax = -INFINITY;
#pragma unroll
    for (int dy = -1; dy <= 1; ++dy) {
#pragma unroll
      for (int dx = -1; dx <= 1; ++dx) {
        const int xx = col + dx;
        if (xx >= 0 && xx < kW) nmax = fmaxf(nmax, ld[tr + dy][xx]);
      }
    }
    const bool peak = (c0 > kThreshold) && (c0 >= nmax);
    cv[i] = peak ? c0 : -INFINITY;
    ci[i] = (r0 + (op >> 7)) * kW + col;  // global pixel index (always real)
  }

  // Per-wave top-10 (butterfly argmax with removal; value then lowest index).
  for (int r = 0; r < kTopK; ++r) {
    float bv = cv[0];
    int bi = ci[0];
#pragma unroll
    for (int i = 1; i < 4; ++i)
      if (cv[i] > bv || (cv[i] == bv && ci[i] < bi)) { bv = cv[i]; bi = ci[i]; }
    for (int off = 1; off < 64; off <<= 1) {
      const float ov = __shfl_xor(bv, off, 64);
      const int oi = __shfl_xor(bi, off, 64);
      if (ov > bv || (ov == bv && oi < bi)) { bv = ov; bi = oi; }
    }
    if (lane == r) { swv[w][r] = bv; swi[w][r] = bi; }
#pragma unroll
    for (int i = 0; i < 4; ++i)
      if (ci[i] == bi) cv[i] = -INFINITY;  // pixel indices are unique
  }
  __syncthreads();

  // Wave 0 merges the 4 wave lists (40 candidates) -> band top-10.
  if (w == 0) {
    float v0 = -INFINITY;
    int i0 = 0x7fffffff;
    if (lane < 4 * kTopK) { v0 = swv[lane / kTopK][lane % kTopK];
                            i0 = swi[lane / kTopK][lane % kTopK]; }
    for (int r = 0; r < kTopK; ++r) {
      float bv = v0;
      int bi = i0;
      for (int off = 1; off < 64; off <<= 1) {
        const float ov = __shfl_xor(bv, off, 64);
        const int oi = __shfl_xor(bi, off, 64);
        if (ov > bv || (ov == bv && oi < bi)) { bv = ov; bi = oi; }
      }
      if (lane == r) {
        cvals[(m * kBands + band) * kTopK + r] = bv;
        cidx[(m * kBands + band) * kTopK + r] = bi;
      }
      if (i0 == bi) { v0 = -INFINITY; i0 = 0x7fffffff; }
    }
  }
}

// ---------------------------------------------------------------------------
// Kernel 3: per map, merge 16 bands x 10 candidates -> global top-10.
// 16 blocks x 1 wave; 3 candidates/lane (192 slots cover 160).
// ---------------------------------------------------------------------------
__global__ __launch_bounds__(64) void merge_kernel(
    const float* __restrict__ cvals, const int* __restrict__ cidx,
    float* __restrict__ tvals, int* __restrict__ tidx) {
  const int m = blockIdx.x;
  const int lane = threadIdx.x;
  float cv[3];
  int ci[3];
#pragma unroll
  for (int q = 0; q < 3; ++q) {
    const int s = lane + 64 * q;
    if (s < kBands * kTopK) {
      cv[q] = cvals[m * kBands * kTopK + s];
      ci[q] = cidx[m * kBands * kTopK + s];
    } else {
      cv[q] = -INFINITY;
      ci[q] = 0x7fffffff;
    }
  }
  for (int r = 0; r < kTopK; ++r) {
    float bv = cv[0];
    int bi = ci[0];
#pragma unroll
    for (int q = 1; q < 3; ++q)
      if (cv[q] > bv || (cv[q] == bv && ci[q] < bi)) { bv = cv[q]; bi = ci[q]; }
    for (int off = 1; off < 64; off <<= 1) {
      const float ov = __shfl_xor(bv, off, 64);
      const int oi = __shfl_xor(bi, off, 64);
      if (ov > bv || (ov == bv && oi < bi)) { bv = ov; bi = oi; }
    }
    if (lane == r) {
      tvals[m * kTopK + r] = bv;
      tidx[m * kTopK + r] = bi;
    }
#pragma unroll
    for (int q = 0; q < 3; ++q)
      if (ci[q] == bi) { cv[q] = -INFINITY; ci[q] = 0x7fffffff; }
  }
}

// ---------------------------------------------------------------------------
// Kernel 4: per sample, gather [10,256] det & loc peak features, compute
// 10x10 cosine sims (norm == top-k intensity value), masked hinge mean.
// ---------------------------------------------------------------------------
__global__ __launch_bounds__(256) void loss_kernel(
    const float* __restrict__ loc, const float* __restrict__ det,
    const float* __restrict__ tvals, const int* __restrict__ tidx,
    float* __restrict__ losses) {
  const int b = blockIdx.x;
  const int t = threadIdx.x;  // channel
  __shared__ float ds[kTopK][kC + 1];
  __shared__ float ls[kTopK][kC + 1];
  __shared__ float s_red[kC];

  float lv[kTopK], dv[kTopK];
  int li[kTopK], di[kTopK];
#pragma unroll
  for (int i = 0; i < kTopK; ++i) {
    lv[i] = tvals[b * kTopK + i];
    li[i] = tidx[b * kTopK + i];
    dv[i] = tvals[(kB + b) * kTopK + i];
    di[i] = tidx[(kB + b) * kTopK + i];
  }
  const float* lb = loc + (size_t)b * kC * kHW + (size_t)t * kHW;
  const float* db = det + (size_t)b * kC * kHW + (size_t)t * kHW;
#pragma unroll
  for (int i = 0; i < kTopK; ++i) {
    ls[i][t] = lb[li[i]];
    ds[i][t] = db[di[i]];
  }
  __syncthreads();

  float contrib = 0.f;
  if (t < kTopK * kTopK) {
    const int i = t / kTopK;  // det peak
    const int j = t % kTopK;  // loc peak
    const bool valid = (dv[i] > -1e30f) && (lv[j] > -1e30f);
    if (valid) {
      float dot = 0.f;
#pragma unroll 8
      for (int c = 0; c < kC; ++c) dot = fmaf(ds[i][c], ls[j][c], dot);
      const float na = fmaxf(dv[i], kEps);
      const float nb = fmaxf(lv[j], kEps);
      const float sim = dot / (na * nb);
      contrib = fmaxf(sim - kMargin, 0.f);
    }
  }
  s_red[t] = contrib;
  __syncthreads();
  if (t == 0) {
    int nd = 0, nl = 0;
    for (int i = 0; i < kTopK; ++i) {
      nd += (dv[i] > -1e30f) ? 1 : 0;
      nl += (lv[i] > -1e30f) ? 1 : 0;
    }
    float s = 0.f;
    for (int k = 0; k < kTopK * kTopK; ++k) s += s_red[k];
    const int np = nd * nl;
    losses[b] = (np > 0) ? (s / (float)np) : 0.f;
  }
}

// ---------------------------------------------------------------------------
// Kernel 5: mean over batch.
// ---------------------------------------------------------------------------
__global__ void final_kernel(const float* __restrict__ losses,
                             float* __restrict__ out) {
  if (threadIdx.x == 0 && blockIdx.x == 0) {
    float s = 0.f;
    for (int i = 0; i < kB; ++i) s += losses[i];
    out[0] = s / (float)kB;
  }
}

extern "C" void kernel_launch(void* const* d_in, const int* in_sizes, int n_in,
                              void* d_out, int out_size, void* d_ws,
                              size_t ws_size, hipStream_t stream) {
  const float* loc = (const float*)d_in[0];
  const float* det = (const float*)d_in[1];
  float* out = (float*)d_out;

  // Workspace (floats): partial [16 maps * 16 groups * 16384] (16 MB) |
  // cvals [16*16*10] | cidx [2560 ints] | tvals [160] | tidx [160] | losses.
  float* wsf = (float*)d_ws;
  float* partial = wsf;
  float* cvals = partial + (size_t)kMaps * kGroups * kHW;
  int* cidx = (int*)(cvals + kMaps * kBands * kTopK);
  float* tvals = (float*)(cidx + kMaps * kBands * kTopK);
  int* tidx = (int*)(tvals + kMaps * kTopK);
  float* losses = (float*)(tidx + kMaps * kTopK);

  sumsq_kernel<<<dim3(kMaps * kGroups * 4), dim3(512), 0, stream>>>(loc, det,
                                                                    partial);
  peaktop_kernel<<<dim3(kMaps * kBands), dim3(256), 0, stream>>>(partial,
                                                                 cvals, cidx);
  merge_kernel<<<dim3(kMaps), dim3(64), 0, stream>>>(cvals, cidx, tvals, tidx);
  loss_kernel<<<dim3(kB), dim3(kC), 0, stream>>>(loc, det, tvals, tidx,
                                                 losses);
  final_kernel<<<dim3(1), dim3(64), 0, stream>>>(losses, out);
}

// Round 4
// 315.053 us; speedup vs baseline: 1.0712x; 1.0712x over previous
//
#include <hip/hip_runtime.h>
#include <math.h>

namespace {
constexpr int kB = 8;
constexpr int kC = 256;
constexpr int kH = 128;
constexpr int kW = 128;
constexpr int kHW = kH * kW;     // 16384
constexpr int kTopK = 10;
constexpr float kThreshold = 0.5f;
constexpr float kMargin = 0.5f;
constexpr float kEps = 1e-8f;
constexpr int kMaps = 2 * kB;            // 8 loc maps then 8 det maps
constexpr int kGrpPlanes = 16;           // channel planes per block (1 MB)
constexpr int kGroups = kC / kGrpPlanes; // 16 groups per map
constexpr int kBands = 16;               // row bands per map (peak/topk)
constexpr int kBandRows = kH / kBands;   // 8 rows per band
typedef float vf4 __attribute__((ext_vector_type(4)));
}

// ---------------------------------------------------------------------------
// Kernel 1: partial[m][g][p] = sum_{c in group g} fmap[c][p]^2.
// NT-LOAD EXPERIMENT (round 4): seven configurations across two sessions
// (LDS accum / register accum, 8-23 waves/CU, 60-90 KB/CU inflight,
// contiguous and strided sweeps, DMA) all pin at 2.2-2.7 TB/s read — the
// MLP/latency theory is falsified; the wall is throughput-like. The input
// is ~LLC-sized and FETCH_SIZE=131 MB shows a 50/50 LLC/HBM split. This
// round's single variable: __builtin_nontemporal_load on the input stream
// (nt = no-allocate/evict-first) to take the LLC out of the read path.
// Values are identical (cache hint only) -> absmax must stay 0.0.
// Structure is round 0's best (101.9 us): 256 blocks x 512 threads, each
// block sweeps a contiguous 1 MB (16 planes), LDS 64 KB accumulator, wave w
// owns pixels [w*2048,(w+1)*2048) so the RMW is race-free, no barriers.
// ---------------------------------------------------------------------------
__global__ __launch_bounds__(512) void sumsq_kernel(
    const float* __restrict__ loc, const float* __restrict__ det,
    float* __restrict__ partial) {
  __shared__ float acc[kHW];  // 64 KB per-block pixel accumulator
  const int bid = blockIdx.x;
  const int m = bid >> 4;   // map 0..15
  const int g = bid & 15;   // plane group 0..15
  const int t = threadIdx.x;
  const int w = t >> 6;     // wave 0..7
  const int lane = t & 63;
  const float* __restrict__ src = (m < kB) ? loc : det;
  const int b = m & (kB - 1);
  const float* base = src + (size_t)b * kC * kHW +
                      (size_t)(g * kGrpPlanes) * kHW + w * 2048 + lane * 4;
  float* lacc = acc + w * 2048 + lane * 4;

  // Plane 0: initialize LDS accumulator.
  {
    vf4 v[8];
#pragma unroll
    for (int i = 0; i < 8; ++i)
      v[i] = __builtin_nontemporal_load((const vf4*)(base + i * 256));
    __builtin_amdgcn_sched_barrier(0);  // all 8 loads issue before any use
#pragma unroll
    for (int i = 0; i < 8; ++i) {
      vf4 o;
      o.x = v[i].x * v[i].x;
      o.y = v[i].y * v[i].y;
      o.z = v[i].z * v[i].z;
      o.w = v[i].w * v[i].w;
      *(vf4*)(lacc + i * 256) = o;
    }
  }
  // Planes 1..15: accumulate.
  for (int j = 1; j < kGrpPlanes; ++j) {
    const float* pb = base + (size_t)j * kHW;
    vf4 v[8];
#pragma unroll
    for (int i = 0; i < 8; ++i)
      v[i] = __builtin_nontemporal_load((const vf4*)(pb + i * 256));
    __builtin_amdgcn_sched_barrier(0);
#pragma unroll
    for (int i = 0; i < 8; ++i) {
      vf4 a = *(const vf4*)(lacc + i * 256);
      a.x = fmaf(v[i].x, v[i].x, a.x);
      a.y = fmaf(v[i].y, v[i].y, a.y);
      a.z = fmaf(v[i].z, v[i].z, a.z);
      a.w = fmaf(v[i].w, v[i].w, a.w);
      *(vf4*)(lacc + i * 256) = a;
    }
  }
  // Dump the wave-private eighth to the block's partial (coalesced 1 KB/inst).
  float* out = partial + ((size_t)m * kGroups + g) * kHW + w * 2048 + lane * 4;
#pragma unroll
  for (int i = 0; i < 8; ++i)
    *(vf4*)(out + i * 256) = *(const vf4*)(lacc + i * 256);
}

// ---------------------------------------------------------------------------
// Kernel 2: fused combine + 3x3 peak mask + BLOCK-LOCAL top-10.
// One block per (map, 8-row band): 256 blocks. Recomputes a 2-row intensity
// halo from partial (group-sum order g=0..15 ascending -> bitwise-identical
// to a separate combine pass), sqrt into an LDS tile, evaluates the peak
// mask, then per-wave shfl-butterfly top-10 + wave-0 merge of the 4 wave
// lists -> 10 (val,idx) candidates per band.
// ---------------------------------------------------------------------------
__global__ __launch_bounds__(256) void peaktop_kernel(
    const float* __restrict__ partial, float* __restrict__ cvals,
    int* __restrict__ cidx) {
  const int m = blockIdx.x >> 4;
  const int band = blockIdx.x & 15;
  const int r0 = band * kBandRows;  // first output row
  const int t = threadIdx.x;        // 0..255
  const int w = t >> 6;
  const int lane = t & 63;
  __shared__ float ld[kBandRows + 2][kW + 4];  // 10 x 132 intensity tile
  __shared__ float swv[4][kTopK];
  __shared__ int swi[4][kTopK];

  // Intensity for rows [r0-1, r0+8]; OOB halo rows become -inf.
  const int prow0 = r0 - 1;  // tile row 0 <-> global row prow0
  float acc[5] = {0.f, 0.f, 0.f, 0.f, 0.f};
  const float* pbase = partial + (size_t)m * kGroups * kHW + prow0 * kW;
#pragma unroll 4
  for (int g = 0; g < kGroups; ++g) {
    const float* pg = pbase + (size_t)g * kHW;
#pragma unroll
    for (int i = 0; i < 5; ++i) {
      const int p = t + 256 * i;  // 0..1279 (10 rows x 128 cols)
      const int gr = prow0 + (p >> 7);
      if (gr >= 0 && gr < kH) acc[i] += pg[p];
    }
  }
#pragma unroll
  for (int i = 0; i < 5; ++i) {
    const int p = t + 256 * i;
    const int gr = prow0 + (p >> 7);
    ld[p >> 7][p & 127] = (gr >= 0 && gr < kH) ? sqrtf(acc[i]) : -INFINITY;
  }
  __syncthreads();

  // Peak candidates for the band's 1024 output pixels (4 per thread).
  float cv[4];
  int ci[4];
#pragma unroll
  for (int i = 0; i < 4; ++i) {
    const int op = t + 256 * i;        // 0..1023
    const int tr = (op >> 7) + 1;      // tile row 1..8
    const int col = op & 127;
    const float c0 = ld[tr][col];
    float nmax = -INFINITY;
#pragma unroll
    for (int dy = -1; dy <= 1; ++dy) {
#pragma unroll
      for (int dx = -1; dx <= 1; ++dx) {
        const int xx = col + dx;
        if (xx >= 0 && xx < kW) nmax = fmaxf(nmax, ld[tr + dy][xx]);
      }
    }
    const bool peak = (c0 > kThreshold) && (c0 >= nmax);
    cv[i] = peak ? c0 : -INFINITY;
    ci[i] = (r0 + (op >> 7)) * kW + col;  // global pixel index (always real)
  }

  // Per-wave top-10 (butterfly argmax with removal; value then lowest index).
  for (int r = 0; r < kTopK; ++r) {
    float bv = cv[0];
    int bi = ci[0];
#pragma unroll
    for (int i = 1; i < 4; ++i)
      if (cv[i] > bv || (cv[i] == bv && ci[i] < bi)) { bv = cv[i]; bi = ci[i]; }
    for (int off = 1; off < 64; off <<= 1) {
      const float ov = __shfl_xor(bv, off, 64);
      const int oi = __shfl_xor(bi, off, 64);
      if (ov > bv || (ov == bv && oi < bi)) { bv = ov; bi = oi; }
    }
    if (lane == r) { swv[w][r] = bv; swi[w][r] = bi; }
#pragma unroll
    for (int i = 0; i < 4; ++i)
      if (ci[i] == bi) cv[i] = -INFINITY;  // pixel indices are unique
  }
  __syncthreads();

  // Wave 0 merges the 4 wave lists (40 candidates) -> band top-10.
  if (w == 0) {
    float v0 = -INFINITY;
    int i0 = 0x7fffffff;
    if (lane < 4 * kTopK) { v0 = swv[lane / kTopK][lane % kTopK];
                            i0 = swi[lane / kTopK][lane % kTopK]; }
    for (int r = 0; r < kTopK; ++r) {
      float bv = v0;
      int bi = i0;
      for (int off = 1; off < 64; off <<= 1) {
        const float ov = __shfl_xor(bv, off, 64);
        const int oi = __shfl_xor(bi, off, 64);
        if (ov > bv || (ov == bv && oi < bi)) { bv = ov; bi = oi; }
      }
      if (lane == r) {
        cvals[(m * kBands + band) * kTopK + r] = bv;
        cidx[(m * kBands + band) * kTopK + r] = bi;
      }
      if (i0 == bi) { v0 = -INFINITY; i0 = 0x7fffffff; }
    }
  }
}

// ---------------------------------------------------------------------------
// Kernel 3: per map, merge 16 bands x 10 candidates -> global top-10.
// 16 blocks x 1 wave; 3 candidates/lane (192 slots cover 160).
// ---------------------------------------------------------------------------
__global__ __launch_bounds__(64) void merge_kernel(
    const float* __restrict__ cvals, const int* __restrict__ cidx,
    float* __restrict__ tvals, int* __restrict__ tidx) {
  const int m = blockIdx.x;
  const int lane = threadIdx.x;
  float cv[3];
  int ci[3];
#pragma unroll
  for (int q = 0; q < 3; ++q) {
    const int s = lane + 64 * q;
    if (s < kBands * kTopK) {
      cv[q] = cvals[m * kBands * kTopK + s];
      ci[q] = cidx[m * kBands * kTopK + s];
    } else {
      cv[q] = -INFINITY;
      ci[q] = 0x7fffffff;
    }
  }
  for (int r = 0; r < kTopK; ++r) {
    float bv = cv[0];
    int bi = ci[0];
#pragma unroll
    for (int q = 1; q < 3; ++q)
      if (cv[q] > bv || (cv[q] == bv && ci[q] < bi)) { bv = cv[q]; bi = ci[q]; }
    for (int off = 1; off < 64; off <<= 1) {
      const float ov = __shfl_xor(bv, off, 64);
      const int oi = __shfl_xor(bi, off, 64);
      if (ov > bv || (ov == bv && oi < bi)) { bv = ov; bi = oi; }
    }
    if (lane == r) {
      tvals[m * kTopK + r] = bv;
      tidx[m * kTopK + r] = bi;
    }
#pragma unroll
    for (int q = 0; q < 3; ++q)
      if (ci[q] == bi) { cv[q] = -INFINITY; ci[q] = 0x7fffffff; }
  }
}

// ---------------------------------------------------------------------------
// Kernel 4: per sample, gather [10,256] det & loc peak features, compute
// 10x10 cosine sims (norm == top-k intensity value), masked hinge mean.
// ---------------------------------------------------------------------------
__global__ __launch_bounds__(256) void loss_kernel(
    const float* __restrict__ loc, const float* __restrict__ det,
    const float* __restrict__ tvals, const int* __restrict__ tidx,
    float* __restrict__ losses) {
  const int b = blockIdx.x;
  const int t = threadIdx.x;  // channel
  __shared__ float ds[kTopK][kC + 1];
  __shared__ float ls[kTopK][kC + 1];
  __shared__ float s_red[kC];

  float lv[kTopK], dv[kTopK];
  int li[kTopK], di[kTopK];
#pragma unroll
  for (int i = 0; i < kTopK; ++i) {
    lv[i] = tvals[b * kTopK + i];
    li[i] = tidx[b * kTopK + i];
    dv[i] = tvals[(kB + b) * kTopK + i];
    di[i] = tidx[(kB + b) * kTopK + i];
  }
  const float* lb = loc + (size_t)b * kC * kHW + (size_t)t * kHW;
  const float* db = det + (size_t)b * kC * kHW + (size_t)t * kHW;
#pragma unroll
  for (int i = 0; i < kTopK; ++i) {
    ls[i][t] = lb[li[i]];
    ds[i][t] = db[di[i]];
  }
  __syncthreads();

  float contrib = 0.f;
  if (t < kTopK * kTopK) {
    const int i = t / kTopK;  // det peak
    const int j = t % kTopK;  // loc peak
    const bool valid = (dv[i] > -1e30f) && (lv[j] > -1e30f);
    if (valid) {
      float dot = 0.f;
#pragma unroll 8
      for (int c = 0; c < kC; ++c) dot = fmaf(ds[i][c], ls[j][c], dot);
      const float na = fmaxf(dv[i], kEps);
      const float nb = fmaxf(lv[j], kEps);
      const float sim = dot / (na * nb);
      contrib = fmaxf(sim - kMargin, 0.f);
    }
  }
  s_red[t] = contrib;
  __syncthreads();
  if (t == 0) {
    int nd = 0, nl = 0;
    for (int i = 0; i < kTopK; ++i) {
      nd += (dv[i] > -1e30f) ? 1 : 0;
      nl += (lv[i] > -1e30f) ? 1 : 0;
    }
    float s = 0.f;
    for (int k = 0; k < kTopK * kTopK; ++k) s += s_red[k];
    const int np = nd * nl;
    losses[b] = (np > 0) ? (s / (float)np) : 0.f;
  }
}

// ---------------------------------------------------------------------------
// Kernel 5: mean over batch.
// ---------------------------------------------------------------------------
__global__ void final_kernel(const float* __restrict__ losses,
                             float* __restrict__ out) {
  if (threadIdx.x == 0 && blockIdx.x == 0) {
    float s = 0.f;
    for (int i = 0; i < kB; ++i) s += losses[i];
    out[0] = s / (float)kB;
  }
}

extern "C" void kernel_launch(void* const* d_in, const int* in_sizes, int n_in,
                              void* d_out, int out_size, void* d_ws,
                              size_t ws_size, hipStream_t stream) {
  const float* loc = (const float*)d_in[0];
  const float* det = (const float*)d_in[1];
  float* out = (float*)d_out;

  // Workspace (floats): partial [16 maps * 16 groups * 16384] (16 MB) |
  // cvals [16*16*10] | cidx [2560 ints] | tvals [160] | tidx [160] | losses.
  float* wsf = (float*)d_ws;
  float* partial = wsf;
  float* cvals = partial + (size_t)kMaps * kGroups * kHW;
  int* cidx = (int*)(cvals + kMaps * kBands * kTopK);
  float* tvals = (float*)(cidx + kMaps * kBands * kTopK);
  int* tidx = (int*)(tvals + kMaps * kTopK);
  float* losses = (float*)(tidx + kMaps * kTopK);

  sumsq_kernel<<<dim3(kMaps * kGroups), dim3(512), 0, stream>>>(loc, det,
                                                                partial);
  peaktop_kernel<<<dim3(kMaps * kBands), dim3(256), 0, stream>>>(partial,
                                                                 cvals, cidx);
  merge_kernel<<<dim3(kMaps), dim3(64), 0, stream>>>(cvals, cidx, tvals, tidx);
  loss_kernel<<<dim3(kB), dim3(kC), 0, stream>>>(loc, det, tvals, tidx,
                                                 losses);
  final_kernel<<<dim3(1), dim3(64), 0, stream>>>(losses, out);
}